// Round 1
// baseline (241.094 us; speedup 1.0000x reference)
//
#include <hip/hip_runtime.h>

// x: (B=32, H=256, W=256, C=16) float32, row-major.
// p[h][w] = mean over (b, c) of x[b][h][w][c]  (512 values per (h,w))
// out = p >= 0.25 ? x*0.25/p : 1 - (0.75/(1-p))*(1-x)  ==  a*x + d
//
// Round 3: LDS-staged single-pass. Round-2 evidence: VGPR_Count=28 < 32
// needed to hold v[8] => the asm pin failed and the compiler rematerialized
// the 8 global loads after the barrier (legal: __restrict__ + pure loads).
// x was read TWICE, with the 2nd read latency-exposed in the store phase.
// Fix: stage the 32 KiB tile in LDS via global_load_lds (16B width, m97
// path). ds_read cannot be rematerialized from global, so the out-phase
// never touches x again. Reduction is remapped to be fully within-wave
// (wave wv owns w_local in [4wv, 4wv+4), lanes cover 4 b-rows per read;
// shfl_xor over bits {0,1} sums c, bits {4,5} sums b-groups) => exactly
// ONE barrier, no cross-wave LDS reduce.
//
// Block = 256 threads (4 waves), one h and a 16-wide w-tile.
// LDS = 32 KiB exactly -> 5 blocks/CU, 20 waves/CU (~same occupancy).

#define ALPHA 0.25f

typedef float v4f __attribute__((ext_vector_type(4)));

__global__ __launch_bounds__(256) void rescale_prob_mask_kernel(
    const float* __restrict__ x, float* __restrict__ out) {
  constexpr int ELEM_PER_B = 256 * 256 * 16;  // 1,048,576 floats per batch

  __shared__ float lds[32][256];  // [b][16w * 16c] = 32 KiB

  const int tile = blockIdx.x;  // 0..4095
  const int h    = tile >> 4;
  const int w0   = (tile & 15) << 4;
  const long tile_base_f = ((long)h * 256 + w0) * 16;  // float offset

  const int t  = threadIdx.x;
  const int l  = t & 63;
  const int wv = t >> 6;

  // ---- stage: wave wv loads rows b = 4k+wv, 1 KiB contiguous each ----
  // global_load_lds: LDS dest = wave-uniform base + lane*16 (linear), so
  // LDS row b is filled in global order: float4 #lane of row (b, h, w-tile).
#pragma unroll
  for (int k = 0; k < 8; ++k) {
    const int b = 4 * k + wv;
    const float* src = x + tile_base_f + (long)b * ELEM_PER_B + l * 4;
    __builtin_amdgcn_global_load_lds(
        (const __attribute__((address_space(1))) unsigned int*)src,
        (__attribute__((address_space(3))) unsigned int*)&lds[b][0],
        16, 0, 0);
  }
  __syncthreads();  // compiler drains vmcnt(0) here — the only barrier

  // ---- reduce, fully within-wave ----
  // Wave wv owns float4 slots [wv*16, wv*16+16) of every row (= w_local in
  // [4wv, 4wv+4)). Lane l reads slot j=(l&15) of row r = 4k + (l>>4).
  const int j = l & 15;
  float4 v[8];
  float s = 0.0f;
#pragma unroll
  for (int k = 0; k < 8; ++k) {
    const int r = 4 * k + (l >> 4);
    v[k] = *(const float4*)&lds[r][wv * 64 + j * 4];  // ds_read_b128
    s += (v[k].x + v[k].y) + (v[k].z + v[k].w);
  }
  // s covers: c-quad (l&3), b-rows {4k + (l>>4)}.  Same w for lanes
  // differing in bits {0,1,4,5}; butterfly those bits:
  s += __shfl_xor(s, 1);
  s += __shfl_xor(s, 2);   // sum over c-quads -> all 16 c
  s += __shfl_xor(s, 16);
  s += __shfl_xor(s, 32);  // sum over b-row groups -> all 32 b
  const float p = s * (1.0f / 512.0f);

  // out = a*x + d
  float a, d;
  if (p >= ALPHA) {
    a = ALPHA / p;
    d = 0.0f;
  } else {
    const float beta = (1.0f - ALPHA) / (1.0f - p);
    a = beta;
    d = 1.0f - beta;
  }

  // ---- out: FMA on LDS-resident values, NT store ----
  // (If the compiler re-reads instead of holding v[], it re-reads LDS —
  //  ~12 cy/b128 — never global. LDS is not written after staging, so no
  //  second barrier is needed.)
#pragma unroll
  for (int k = 0; k < 8; ++k) {
    const int r = 4 * k + (l >> 4);
    v4f o;
    o.x = fmaf(a, v[k].x, d);
    o.y = fmaf(a, v[k].y, d);
    o.z = fmaf(a, v[k].z, d);
    o.w = fmaf(a, v[k].w, d);
    // 16-lane groups store 256 B contiguous (4 full 64B lines per group).
    float* dst = out + tile_base_f + (long)r * ELEM_PER_B + (wv * 16 + j) * 4;
    __builtin_nontemporal_store(o, (v4f*)dst);
  }
}

extern "C" void kernel_launch(void* const* d_in, const int* in_sizes, int n_in,
                              void* d_out, int out_size, void* d_ws, size_t ws_size,
                              hipStream_t stream) {
  const float* x = (const float*)d_in[0];
  float* out = (float*)d_out;
  // 256 h * 16 w-tiles = 4096 blocks
  rescale_prob_mask_kernel<<<dim3(4096), dim3(256), 0, stream>>>(x, out);
}